// Round 1
// baseline (664.531 us; speedup 1.0000x reference)
//
#include <hip/hip_runtime.h>
#include <hip/hip_bf16.h>
#include <cstdint>
#include <cstddef>

#define N_NODES 100000
#define N_EDGES 3200000
#define IN_DIM  256
#define HID_DIM 64
#define OUT_DIM 32
#define SLOT_STRIDE 96   // max in-degree headroom; Poisson(32), P(>=96) ~ 4e-20

// ---------------- adjacency build ----------------
__global__ void k_fill(const int* __restrict__ ei, int* __restrict__ ecnt,
                       int* __restrict__ slots) {
    int e = blockIdx.x * blockDim.x + threadIdx.x;
    if (e >= N_EDGES) return;
    int s = ei[e];            // edge_index[0][e]
    int d = ei[N_EDGES + e];  // edge_index[1][e]
    int pos = atomicAdd(&ecnt[d], 1);
    if (pos < SLOT_STRIDE) slots[d * SLOT_STRIDE + pos] = s;
}

__global__ void k_dn(const int* __restrict__ ecnt, float* __restrict__ dn) {
    int n = blockIdx.x * blockDim.x + threadIdx.x;
    if (n < N_NODES) dn[n] = rsqrtf((float)ecnt[n] + 1.0f);  // +1 self-loop
}

// ---------------- tiled fp32 GEMM: Y[M,NC] = X[M,KD] @ W[KD,NC] ----------------
// 128 rows/block, thread tile 4 rows x 8 cols, thread grid 32 x (NC/8).
template<int KD, int NC>
__global__ __launch_bounds__(32 * (NC / 8))
void k_gemm(const float* __restrict__ X, const float* __restrict__ W,
            float* __restrict__ Y, int M) {
    constexpr int TC = NC / 8;        // thread cols groups
    constexpr int THREADS = 32 * TC;
    constexpr int KC = 32;            // k chunk
    __shared__ float Xs[128][33];     // pad 33: conflict-free column reads
    __shared__ float Ws[KC][NC];

    const int tid = threadIdx.x;
    const int tr  = tid / TC;         // 0..31
    const int tc  = tid % TC;         // 0..TC-1
    const int row0 = blockIdx.x * 128;

    float acc[4][8];
    #pragma unroll
    for (int i = 0; i < 4; ++i)
        #pragma unroll
        for (int j = 0; j < 8; ++j) acc[i][j] = 0.f;

    for (int kc = 0; kc < KD; kc += KC) {
        // stage X tile: 128 x KC
        #pragma unroll
        for (int i = tid; i < 128 * (KC / 4); i += THREADS) {
            int r  = i / (KC / 4);
            int k4 = (i % (KC / 4)) * 4;
            float4 v = make_float4(0.f, 0.f, 0.f, 0.f);
            int gr = row0 + r;
            if (gr < M)
                v = *reinterpret_cast<const float4*>(&X[(size_t)gr * KD + kc + k4]);
            Xs[r][k4 + 0] = v.x; Xs[r][k4 + 1] = v.y;
            Xs[r][k4 + 2] = v.z; Xs[r][k4 + 3] = v.w;
        }
        // stage W chunk: KC x NC
        #pragma unroll
        for (int i = tid; i < KC * (NC / 4); i += THREADS) {
            int kk = i / (NC / 4);
            int c4 = (i % (NC / 4)) * 4;
            *reinterpret_cast<float4*>(&Ws[kk][c4]) =
                *reinterpret_cast<const float4*>(&W[(size_t)(kc + kk) * NC + c4]);
        }
        __syncthreads();

        #pragma unroll
        for (int kk = 0; kk < KC; ++kk) {
            float xv[4];
            #pragma unroll
            for (int i = 0; i < 4; ++i) xv[i] = Xs[tr * 4 + i][kk];
            float4 w0 = *reinterpret_cast<const float4*>(&Ws[kk][tc * 8]);
            float4 w1 = *reinterpret_cast<const float4*>(&Ws[kk][tc * 8 + 4]);
            float wv[8] = {w0.x, w0.y, w0.z, w0.w, w1.x, w1.y, w1.z, w1.w};
            #pragma unroll
            for (int i = 0; i < 4; ++i)
                #pragma unroll
                for (int j = 0; j < 8; ++j)
                    acc[i][j] = fmaf(xv[i], wv[j], acc[i][j]);
        }
        __syncthreads();
    }

    #pragma unroll
    for (int i = 0; i < 4; ++i) {
        int gr = row0 + tr * 4 + i;
        if (gr < M) {
            float4 o0 = make_float4(acc[i][0], acc[i][1], acc[i][2], acc[i][3]);
            float4 o1 = make_float4(acc[i][4], acc[i][5], acc[i][6], acc[i][7]);
            *reinterpret_cast<float4*>(&Y[(size_t)gr * NC + tc * 8])     = o0;
            *reinterpret_cast<float4*>(&Y[(size_t)gr * NC + tc * 8 + 4]) = o1;
        }
    }
}

// ---------------- layer-1 aggregation (+bias+relu), 64 features ----------------
// one wave per node; lane = feature
__global__ void k_agg1(const float* __restrict__ H1, const int* __restrict__ slots,
                       const int* __restrict__ ecnt, const float* __restrict__ dn,
                       const float* __restrict__ b1, float* __restrict__ out1) {
    int wid  = (blockIdx.x * blockDim.x + threadIdx.x) >> 6;
    int lane = threadIdx.x & 63;
    if (wid >= N_NODES) return;
    const int n = wid;
    const int cnt = ecnt[n];
    const float dnn = dn[n];
    float acc = dnn * H1[(size_t)n * HID_DIM + lane];   // self-loop
    const int base = n * SLOT_STRIDE;
    for (int b0 = 0; b0 < cnt; b0 += 64) {
        int m = min(64, cnt - b0);
        int s = 0; float ds = 0.f;
        if (lane < m) { s = slots[base + b0 + lane]; ds = dn[s]; }
        for (int j = 0; j < m; ++j) {
            int   sj  = __shfl(s,  j);
            float dsj = __shfl(ds, j);
            acc = fmaf(dsj, H1[(size_t)sj * HID_DIM + lane], acc);
        }
    }
    out1[(size_t)n * HID_DIM + lane] = fmaxf(b1[lane] + dnn * acc, 0.f);
}

// ---------------- layer-2 aggregation (+bias), 32 features ----------------
// one wave per node; two 32-lane halves each take alternate edges
__global__ void k_agg2(const float* __restrict__ H2, const int* __restrict__ slots,
                       const int* __restrict__ ecnt, const float* __restrict__ dn,
                       const float* __restrict__ b2, float* __restrict__ out) {
    int wid  = (blockIdx.x * blockDim.x + threadIdx.x) >> 6;
    int lane = threadIdx.x & 63;
    if (wid >= N_NODES) return;
    const int n = wid;
    const int cnt = ecnt[n];
    const float dnn = dn[n];
    const int f = lane & 31;
    const int h = lane >> 5;
    float acc = (h == 0) ? dnn * H2[(size_t)n * OUT_DIM + f] : 0.f;
    const int base = n * SLOT_STRIDE;
    for (int b0 = 0; b0 < cnt; b0 += 64) {
        int m = min(64, cnt - b0);
        int s = 0; float ds = 0.f;
        if (lane < m) { s = slots[base + b0 + lane]; ds = dn[s]; }
        for (int j = h; j < m; j += 2) {
            int   sj  = __shfl(s,  j);
            float dsj = __shfl(ds, j);
            acc = fmaf(dsj, H2[(size_t)sj * OUT_DIM + f], acc);
        }
    }
    acc += __shfl_xor(acc, 32);
    if (h == 0) out[(size_t)n * OUT_DIM + f] = b2[f] + dnn * acc;
}

// ---------------- MLP head: relu(h@Wp1+bp1) @ Wp2 + bp2 -> sigmoid ----------------
// one wave per node; lane = hidden col (64)
__global__ void k_mlp(const float* __restrict__ H, const float* __restrict__ Wp1,
                      const float* __restrict__ bp1, const float* __restrict__ Wp2,
                      const float* __restrict__ bp2, float* __restrict__ outw) {
    int wid  = (blockIdx.x * blockDim.x + threadIdx.x) >> 6;
    int lane = threadIdx.x & 63;
    if (wid >= N_NODES) return;
    const int n = wid;
    float hv = (lane < OUT_DIM) ? H[(size_t)n * OUT_DIM + lane] : 0.f;
    float acc = bp1[lane];
    #pragma unroll
    for (int f = 0; f < OUT_DIM; ++f) {
        float hf = __shfl(hv, f);
        acc = fmaf(hf, Wp1[f * HID_DIM + lane], acc);
    }
    acc = fmaxf(acc, 0.f);
    float z = acc * Wp2[lane];
    #pragma unroll
    for (int off = 32; off; off >>= 1) z += __shfl_xor(z, off);
    if (lane == 0) outw[n] = 1.f / (1.f + __expf(-(z + bp2[0])));
}

// ---------------- launcher ----------------
extern "C" void kernel_launch(void* const* d_in, const int* in_sizes, int n_in,
                              void* d_out, int out_size, void* d_ws, size_t ws_size,
                              hipStream_t stream) {
    const float* x   = (const float*)d_in[0];
    const int*   ei  = (const int*)d_in[1];
    const float* W1  = (const float*)d_in[2];
    const float* b1  = (const float*)d_in[3];
    const float* W2  = (const float*)d_in[4];
    const float* b2  = (const float*)d_in[5];
    const float* Wp1 = (const float*)d_in[6];
    const float* bp1 = (const float*)d_in[7];
    const float* Wp2 = (const float*)d_in[8];
    const float* bp2 = (const float*)d_in[9];
    float* out = (float*)d_out;

    char* ws = (char*)d_ws;
    // offsets (all 256B-aligned)
    int*   ecnt  = (int*)  (ws + 0);                     //   400,000 B
    float* dn    = (float*)(ws + 400384);                //   400,000 B
    int*   slots = (int*)  (ws + 800768);                //  38,400,000 B
    float* H1    = (float*)(ws + 39201024);              //  25,600,000 B
    float* out1  = (float*)(ws + 64801024);              //  25,600,000 B
    float* H2    = (float*)(ws + 90401024);              //  12,800,000 B
    // end ~103.2 MB

    hipMemsetAsync(ecnt, 0, N_NODES * sizeof(int), stream);

    k_fill<<<N_EDGES / 256, 256, 0, stream>>>(ei, ecnt, slots);
    k_dn<<<(N_NODES + 255) / 256, 256, 0, stream>>>(ecnt, dn);

    k_gemm<IN_DIM, HID_DIM><<<(N_NODES + 127) / 128, 256, 0, stream>>>(x, W1, H1, N_NODES);
    k_agg1<<<(N_NODES * 64 + 255) / 256, 256, 0, stream>>>(H1, slots, ecnt, dn, b1, out1);

    k_gemm<HID_DIM, OUT_DIM><<<(N_NODES + 127) / 128, 128, 0, stream>>>(out1, W2, H2, N_NODES);
    k_agg2<<<(N_NODES * 64 + 255) / 256, 256, 0, stream>>>(H2, slots, ecnt, dn, b2, out);

    k_mlp<<<(N_NODES * 64 + 255) / 256, 256, 0, stream>>>(out, Wp1, bp1, Wp2, bp2,
                                                          out + (size_t)N_NODES * OUT_DIM);
}

// Round 2
// 457.671 us; speedup vs baseline: 1.4520x; 1.4520x over previous
//
#include <hip/hip_runtime.h>
#include <hip/hip_bf16.h>
#include <cstdint>
#include <cstddef>

#define N_NODES 100000
#define N_EDGES 3200000
#define IN_DIM  256
#define HID_DIM 64
#define OUT_DIM 32

#define NBINS      391        // ceil(100000/256) nodes per bin = 256
#define BIN_SHIFT  8
#define BIN_STRIDE 9216       // max edges/bin; lambda=8192, +11 sigma headroom
#define BIN_EPB    8192       // edges per k_bin block

// ---------------- pass 1: bin edges by dst>>8, coalesced segment writes ----------------
__global__ __launch_bounds__(512)
void k_bin(const int* __restrict__ ei, int* __restrict__ bin_cursor,
           int2* __restrict__ binned) {
    __shared__ int  lcount[NBINS];
    __shared__ int  lstart[NBINS];
    __shared__ int  lplace[NBINS];
    __shared__ int  gbase[NBINS];
    __shared__ int  sc[512];
    __shared__ int2 stage[BIN_EPB];   // 64 KB

    const int tid  = threadIdx.x;
    const int e0   = blockIdx.x * BIN_EPB;
    const int nval = min(BIN_EPB, N_EDGES - e0);

    for (int i = tid; i < NBINS; i += 512) lcount[i] = 0;
    __syncthreads();

    #pragma unroll
    for (int k = 0; k < BIN_EPB / 512; ++k) {
        int e = e0 + k * 512 + tid;
        if (e < N_EDGES) atomicAdd(&lcount[ei[N_EDGES + e] >> BIN_SHIFT], 1);
    }
    __syncthreads();

    // inclusive Hillis-Steele scan over 512-padded counts
    int v = (tid < NBINS) ? lcount[tid] : 0;
    sc[tid] = v; __syncthreads();
    for (int off = 1; off < 512; off <<= 1) {
        int x = sc[tid];
        if (tid >= off) x += sc[tid - off];
        __syncthreads(); sc[tid] = x; __syncthreads();
    }
    if (tid < NBINS) {
        int excl = sc[tid] - v;
        lstart[tid] = excl;
        lplace[tid] = excl;
        gbase[tid]  = atomicAdd(&bin_cursor[tid], v);
    }
    __syncthreads();

    #pragma unroll
    for (int k = 0; k < BIN_EPB / 512; ++k) {
        int e = e0 + k * 512 + tid;
        if (e < N_EDGES) {
            int s = ei[e];
            int d = ei[N_EDGES + e];
            int p = atomicAdd(&lplace[d >> BIN_SHIFT], 1);
            stage[p] = make_int2(s, d);
        }
    }
    __syncthreads();

    // flush: consecutive i within a bin segment -> consecutive global (coalesced)
    for (int i = tid; i < nval; i += 512) {
        int2 ed  = stage[i];
        int  b   = ed.y >> BIN_SHIFT;
        int  gix = gbase[b] + (i - lstart[b]);
        if (gix < BIN_STRIDE)
            binned[(size_t)b * BIN_STRIDE + gix] = ed;
    }
}

// ---------------- bin-count exclusive scan (1 block) ----------------
__global__ __launch_bounds__(512)
void k_binscan(const int* __restrict__ bin_cursor, int* __restrict__ bin_base,
               int* __restrict__ rowptr) {
    __shared__ int sc[512];
    int t = threadIdx.x;
    int v = (t < NBINS) ? min(bin_cursor[t], BIN_STRIDE) : 0;
    sc[t] = v; __syncthreads();
    for (int off = 1; off < 512; off <<= 1) {
        int x = sc[t];
        if (t >= off) x += sc[t - off];
        __syncthreads(); sc[t] = x; __syncthreads();
    }
    if (t < NBINS)     bin_base[t] = sc[t] - v;
    if (t == NBINS - 1) rowptr[N_NODES] = sc[t];
}

// ---------------- pass 2: per-bin LDS counting sort -> CSR (+dn) ----------------
__global__ __launch_bounds__(256)
void k_csr(const int2* __restrict__ binned, const int* __restrict__ bin_cursor,
           const int* __restrict__ bin_base, int* __restrict__ rowptr,
           float* __restrict__ dn, int* __restrict__ csr) {
    __shared__ int lcnt[256];
    __shared__ int lpl[256];
    __shared__ int sc[256];
    __shared__ int csr_s[BIN_STRIDE];   // 36.9 KB

    const int tid   = threadIdx.x;
    const int b     = blockIdx.x;
    const int n0    = b << BIN_SHIFT;
    const int cnt   = min(bin_cursor[b], BIN_STRIDE);
    const int ebase = bin_base[b];
    const int2* bb  = binned + (size_t)b * BIN_STRIDE;

    lcnt[tid] = 0;
    __syncthreads();
    for (int i = tid; i < cnt; i += 256)
        atomicAdd(&lcnt[bb[i].y & 255], 1);
    __syncthreads();

    int v = lcnt[tid];
    sc[tid] = v; __syncthreads();
    for (int off = 1; off < 256; off <<= 1) {
        int x = sc[tid];
        if (tid >= off) x += sc[tid - off];
        __syncthreads(); sc[tid] = x; __syncthreads();
    }
    int excl = sc[tid] - v;
    lpl[tid] = excl;
    int n = n0 + tid;
    if (n < N_NODES) {
        rowptr[n] = ebase + excl;
        dn[n]     = rsqrtf((float)v + 1.0f);   // +1 self-loop
    }
    __syncthreads();

    for (int i = tid; i < cnt; i += 256) {
        int2 ed = bb[i];
        int  p  = atomicAdd(&lpl[ed.y & 255], 1);
        csr_s[p] = ed.x;
    }
    __syncthreads();
    for (int i = tid; i < cnt; i += 256)
        csr[ebase + i] = csr_s[i];   // coalesced
}

// ---------------- tiled fp32 GEMM: Y[M,NC] = X[M,KD] @ W[KD,NC] ----------------
template<int KD, int NC>
__global__ __launch_bounds__(32 * (NC / 8))
void k_gemm(const float* __restrict__ X, const float* __restrict__ W,
            float* __restrict__ Y, int M) {
    constexpr int TC = NC / 8;
    constexpr int THREADS = 32 * TC;
    constexpr int KC = 32;
    __shared__ float Xs[128][33];
    __shared__ float Ws[KC][NC];

    const int tid  = threadIdx.x;
    const int tr   = tid / TC;
    const int tc   = tid % TC;
    const int row0 = blockIdx.x * 128;

    float acc[4][8];
    #pragma unroll
    for (int i = 0; i < 4; ++i)
        #pragma unroll
        for (int j = 0; j < 8; ++j) acc[i][j] = 0.f;

    for (int kc = 0; kc < KD; kc += KC) {
        #pragma unroll
        for (int i = tid; i < 128 * (KC / 4); i += THREADS) {
            int r  = i / (KC / 4);
            int k4 = (i % (KC / 4)) * 4;
            float4 v = make_float4(0.f, 0.f, 0.f, 0.f);
            int gr = row0 + r;
            if (gr < M)
                v = *reinterpret_cast<const float4*>(&X[(size_t)gr * KD + kc + k4]);
            Xs[r][k4 + 0] = v.x; Xs[r][k4 + 1] = v.y;
            Xs[r][k4 + 2] = v.z; Xs[r][k4 + 3] = v.w;
        }
        #pragma unroll
        for (int i = tid; i < KC * (NC / 4); i += THREADS) {
            int kk = i / (NC / 4);
            int c4 = (i % (NC / 4)) * 4;
            *reinterpret_cast<float4*>(&Ws[kk][c4]) =
                *reinterpret_cast<const float4*>(&W[(size_t)(kc + kk) * NC + c4]);
        }
        __syncthreads();

        #pragma unroll
        for (int kk = 0; kk < KC; ++kk) {
            float xv[4];
            #pragma unroll
            for (int i = 0; i < 4; ++i) xv[i] = Xs[tr * 4 + i][kk];
            float4 w0 = *reinterpret_cast<const float4*>(&Ws[kk][tc * 8]);
            float4 w1 = *reinterpret_cast<const float4*>(&Ws[kk][tc * 8 + 4]);
            float wv[8] = {w0.x, w0.y, w0.z, w0.w, w1.x, w1.y, w1.z, w1.w};
            #pragma unroll
            for (int i = 0; i < 4; ++i)
                #pragma unroll
                for (int j = 0; j < 8; ++j)
                    acc[i][j] = fmaf(xv[i], wv[j], acc[i][j]);
        }
        __syncthreads();
    }

    #pragma unroll
    for (int i = 0; i < 4; ++i) {
        int gr = row0 + tr * 4 + i;
        if (gr < M) {
            float4 o0 = make_float4(acc[i][0], acc[i][1], acc[i][2], acc[i][3]);
            float4 o1 = make_float4(acc[i][4], acc[i][5], acc[i][6], acc[i][7]);
            *reinterpret_cast<float4*>(&Y[(size_t)gr * NC + tc * 8])     = o0;
            *reinterpret_cast<float4*>(&Y[(size_t)gr * NC + tc * 8 + 4]) = o1;
        }
    }
}

// ---------------- agg1 (+bias+relu) fused with GEMM2 -> H2 ----------------
// one wave per node; lane = feature (64)
__global__ __launch_bounds__(256)
void k_agg1(const float* __restrict__ H1, const int* __restrict__ rowptr,
            const int* __restrict__ csr, const float* __restrict__ dn,
            const float* __restrict__ b1, const float* __restrict__ W2,
            float* __restrict__ H2) {
    __shared__ float W2s[HID_DIM * OUT_DIM];   // 8 KB
    for (int i = threadIdx.x; i < HID_DIM * OUT_DIM; i += 256) W2s[i] = W2[i];
    __syncthreads();

    int wid  = (blockIdx.x * blockDim.x + threadIdx.x) >> 6;
    int lane = threadIdx.x & 63;
    if (wid >= N_NODES) return;
    const int n = wid;

    int rp = (lane < 2) ? rowptr[n + lane] : 0;
    int base = __shfl(rp, 0);
    int cnt  = __shfl(rp, 1) - base;
    const float dnn = dn[n];

    float acc = dnn * H1[(size_t)n * HID_DIM + lane];   // self-loop
    for (int b0 = 0; b0 < cnt; b0 += 64) {
        int m = min(64, cnt - b0);
        int s = 0; float ds = 0.f;
        if (lane < m) { s = csr[base + b0 + lane]; ds = dn[s]; }
        for (int j = 0; j < m; ++j) {
            int   sj  = __shfl(s,  j);
            float dsj = __shfl(ds, j);
            acc = fmaf(dsj, H1[(size_t)sj * HID_DIM + lane], acc);
        }
    }
    float o = fmaxf(b1[lane] + dnn * acc, 0.f);   // out1 row, one per lane

    // fused GEMM2: H2[n][c] = sum_f o_f * W2[f][c]; halves split f-range
    const int c = lane & 31, h = lane >> 5;
    float acc2 = 0.f;
    #pragma unroll
    for (int fi = 0; fi < 32; ++fi) {
        int fg = h * 32 + fi;
        float v = __shfl(o, fg);
        acc2 = fmaf(v, W2s[fg * OUT_DIM + c], acc2);
    }
    acc2 += __shfl_xor(acc2, 32);
    if (h == 0) H2[(size_t)n * OUT_DIM + c] = acc2;
}

// ---------------- agg2 (+bias) fused with MLP head ----------------
// one wave per node; lane&31 = feature, halves split edges
__global__ __launch_bounds__(256)
void k_agg2m(const float* __restrict__ H2, const int* __restrict__ rowptr,
             const int* __restrict__ csr, const float* __restrict__ dn,
             const float* __restrict__ b2, const float* __restrict__ Wp1,
             const float* __restrict__ bp1, const float* __restrict__ Wp2,
             const float* __restrict__ bp2, float* __restrict__ out_h,
             float* __restrict__ out_w) {
    __shared__ float Wp1s[OUT_DIM * HID_DIM];  // 8 KB
    __shared__ float Wp2s[HID_DIM];
    __shared__ float bp1s[HID_DIM];
    for (int i = threadIdx.x; i < OUT_DIM * HID_DIM; i += 256) Wp1s[i] = Wp1[i];
    if (threadIdx.x < HID_DIM) {
        Wp2s[threadIdx.x] = Wp2[threadIdx.x];
        bp1s[threadIdx.x] = bp1[threadIdx.x];
    }
    __syncthreads();

    int wid  = (blockIdx.x * blockDim.x + threadIdx.x) >> 6;
    int lane = threadIdx.x & 63;
    if (wid >= N_NODES) return;
    const int n = wid;

    int rp = (lane < 2) ? rowptr[n + lane] : 0;
    int base = __shfl(rp, 0);
    int cnt  = __shfl(rp, 1) - base;
    const float dnn = dn[n];
    const int f = lane & 31, h = lane >> 5;

    float acc = (h == 0) ? dnn * H2[(size_t)n * OUT_DIM + f] : 0.f;
    for (int b0 = 0; b0 < cnt; b0 += 64) {
        int m = min(64, cnt - b0);
        int s = 0; float ds = 0.f;
        if (lane < m) { s = csr[base + b0 + lane]; ds = dn[s]; }
        for (int j = h; j < m; j += 2) {
            int   sj  = __shfl(s,  j);
            float dsj = __shfl(ds, j);
            acc = fmaf(dsj, H2[(size_t)sj * OUT_DIM + f], acc);
        }
    }
    acc += __shfl_xor(acc, 32);                 // both halves now hold full sum
    float hv = b2[f] + dnn * acc;               // h[n][f] on lane f and f+32
    if (h == 0) out_h[(size_t)n * OUT_DIM + f] = hv;

    // MLP: p[j] = relu(bp1[j] + sum_f h[f]*Wp1[f][j]), j = lane (64)
    float p = bp1s[lane];
    #pragma unroll
    for (int ff = 0; ff < OUT_DIM; ++ff) {
        float hf = __shfl(hv, ff);
        p = fmaf(hf, Wp1s[ff * HID_DIM + lane], p);
    }
    p = fmaxf(p, 0.f);
    float z = p * Wp2s[lane];
    #pragma unroll
    for (int off = 32; off; off >>= 1) z += __shfl_xor(z, off);
    if (lane == 0) out_w[n] = 1.f / (1.f + __expf(-(z + bp2[0])));
}

// ---------------- launcher ----------------
extern "C" void kernel_launch(void* const* d_in, const int* in_sizes, int n_in,
                              void* d_out, int out_size, void* d_ws, size_t ws_size,
                              hipStream_t stream) {
    const float* x   = (const float*)d_in[0];
    const int*   ei  = (const int*)d_in[1];
    const float* W1  = (const float*)d_in[2];
    const float* b1  = (const float*)d_in[3];
    const float* W2  = (const float*)d_in[4];
    const float* b2  = (const float*)d_in[5];
    const float* Wp1 = (const float*)d_in[6];
    const float* bp1 = (const float*)d_in[7];
    const float* Wp2 = (const float*)d_in[8];
    const float* bp2 = (const float*)d_in[9];
    float* out = (float*)d_out;

    char* ws = (char*)d_ws;
    int*   bin_cursor = (int*)  (ws + 0);           //  1,564 B
    int*   bin_base   = (int*)  (ws + 2048);        //  1,564 B
    int*   rowptr     = (int*)  (ws + 4096);        //  400,004 B
    float* dn         = (float*)(ws + 404480);      //  400,000 B
    int*   csr        = (int*)  (ws + 804608);      //  12,800,000 B
    int2*  binned     = (int2*) (ws + 13604608);    //  28,827,648 B
    float* H1         = (float*)(ws + 42432512);    //  25,600,000 B
    float* H2         = (float*)(ws + 68032512);    //  12,800,000 B
    // end ~80.8 MB

    hipMemsetAsync(bin_cursor, 0, NBINS * sizeof(int), stream);

    k_bin<<<(N_EDGES + BIN_EPB - 1) / BIN_EPB, 512, 0, stream>>>(ei, bin_cursor, binned);
    k_binscan<<<1, 512, 0, stream>>>(bin_cursor, bin_base, rowptr);
    k_csr<<<NBINS, 256, 0, stream>>>(binned, bin_cursor, bin_base, rowptr, dn, csr);

    k_gemm<IN_DIM, HID_DIM><<<(N_NODES + 127) / 128, 256, 0, stream>>>(x, W1, H1, N_NODES);

    k_agg1<<<(N_NODES + 3) / 4, 256, 0, stream>>>(H1, rowptr, csr, dn, b1, W2, H2);
    k_agg2m<<<(N_NODES + 3) / 4, 256, 0, stream>>>(H2, rowptr, csr, dn, b2,
                                                   Wp1, bp1, Wp2, bp2,
                                                   out, out + (size_t)N_NODES * OUT_DIM);
}

// Round 5
// 353.703 us; speedup vs baseline: 1.8788x; 1.2939x over previous
//
#include <hip/hip_runtime.h>
#include <hip/hip_bf16.h>
#include <cstdint>
#include <cstddef>

#define N_NODES 100000
#define N_EDGES 3200000
#define IN_DIM  256
#define HID_DIM 64
#define OUT_DIM 32

#define NBINS      391        // ceil(100000/256), 256 nodes per bin
#define BIN_SHIFT  8
#define BIN_STRIDE 9216       // lambda=8192, +11 sigma headroom
#define BIN_EPB    8192

// ---------------- pass 1: bin edges by dst>>8, coalesced segment writes ----------------
__global__ __launch_bounds__(512)
void k_bin(const int* __restrict__ ei, int* __restrict__ bin_cursor,
           int2* __restrict__ binned) {
    __shared__ int  lcount[NBINS];
    __shared__ int  lstart[NBINS];
    __shared__ int  lplace[NBINS];
    __shared__ int  gbase[NBINS];
    __shared__ int  sc[512];
    __shared__ int2 stage[BIN_EPB];   // 64 KB

    const int tid  = threadIdx.x;
    const int e0   = blockIdx.x * BIN_EPB;
    const int nval = min(BIN_EPB, N_EDGES - e0);

    for (int i = tid; i < NBINS; i += 512) lcount[i] = 0;
    __syncthreads();

    #pragma unroll
    for (int k = 0; k < BIN_EPB / 512; ++k) {
        int e = e0 + k * 512 + tid;
        if (e < N_EDGES) atomicAdd(&lcount[ei[N_EDGES + e] >> BIN_SHIFT], 1);
    }
    __syncthreads();

    int v = (tid < NBINS) ? lcount[tid] : 0;
    sc[tid] = v; __syncthreads();
    for (int off = 1; off < 512; off <<= 1) {
        int x = sc[tid];
        if (tid >= off) x += sc[tid - off];
        __syncthreads(); sc[tid] = x; __syncthreads();
    }
    if (tid < NBINS) {
        int excl = sc[tid] - v;
        lstart[tid] = excl;
        lplace[tid] = excl;
        gbase[tid]  = atomicAdd(&bin_cursor[tid], v);
    }
    __syncthreads();

    #pragma unroll
    for (int k = 0; k < BIN_EPB / 512; ++k) {
        int e = e0 + k * 512 + tid;
        if (e < N_EDGES) {
            int s = ei[e];
            int d = ei[N_EDGES + e];
            int p = atomicAdd(&lplace[d >> BIN_SHIFT], 1);
            stage[p] = make_int2(s, d);
        }
    }
    __syncthreads();

    for (int i = tid; i < nval; i += 512) {
        int2 ed  = stage[i];
        int  b   = ed.y >> BIN_SHIFT;
        int  gix = gbase[b] + (i - lstart[b]);
        if (gix < BIN_STRIDE)
            binned[(size_t)b * BIN_STRIDE + gix] = ed;
    }
}

// ---------------- bin-count exclusive scan (1 block) ----------------
__global__ __launch_bounds__(512)
void k_binscan(const int* __restrict__ bin_cursor, int* __restrict__ bin_base,
               int* __restrict__ rowptr) {
    __shared__ int sc[512];
    int t = threadIdx.x;
    int v = (t < NBINS) ? min(bin_cursor[t], BIN_STRIDE) : 0;
    sc[t] = v; __syncthreads();
    for (int off = 1; off < 512; off <<= 1) {
        int x = sc[t];
        if (t >= off) x += sc[t - off];
        __syncthreads(); sc[t] = x; __syncthreads();
    }
    if (t < NBINS)      bin_base[t] = sc[t] - v;
    if (t == NBINS - 1) rowptr[N_NODES] = sc[t];
}

// ---------------- pass 2: per-bin LDS counting sort -> CSR (+dn) ----------------
__global__ __launch_bounds__(256)
void k_csr(const int2* __restrict__ binned, const int* __restrict__ bin_cursor,
           const int* __restrict__ bin_base, int* __restrict__ rowptr,
           float* __restrict__ dn, int* __restrict__ csr) {
    __shared__ int lcnt[256];
    __shared__ int lpl[256];
    __shared__ int sc[256];
    __shared__ int csr_s[BIN_STRIDE];   // 36.9 KB

    const int tid   = threadIdx.x;
    const int b     = blockIdx.x;
    const int n0    = b << BIN_SHIFT;
    const int cnt   = min(bin_cursor[b], BIN_STRIDE);
    const int ebase = bin_base[b];
    const int2* bb  = binned + (size_t)b * BIN_STRIDE;

    lcnt[tid] = 0;
    __syncthreads();
    for (int i = tid; i < cnt; i += 256)
        atomicAdd(&lcnt[bb[i].y & 255], 1);
    __syncthreads();

    int v = lcnt[tid];
    sc[tid] = v; __syncthreads();
    for (int off = 1; off < 256; off <<= 1) {
        int x = sc[tid];
        if (tid >= off) x += sc[tid - off];
        __syncthreads(); sc[tid] = x; __syncthreads();
    }
    int excl = sc[tid] - v;
    lpl[tid] = excl;
    int n = n0 + tid;
    if (n < N_NODES) {
        rowptr[n] = ebase + excl;
        dn[n]     = rsqrtf((float)v + 1.0f);   // +1 self-loop
    }
    __syncthreads();

    for (int i = tid; i < cnt; i += 256) {
        int2 ed = bb[i];
        int  p  = atomicAdd(&lpl[ed.y & 255], 1);
        csr_s[p] = ed.x;
    }
    __syncthreads();
    for (int i = tid; i < cnt; i += 256)
        csr[ebase + i] = csr_s[i];
}

// ---------------- tiled fp32 GEMM: Y[M,NC] = X[M,KD] @ W[KD,NC] ----------------
template<int KD, int NC>
__global__ __launch_bounds__(32 * (NC / 8))
void k_gemm(const float* __restrict__ X, const float* __restrict__ W,
            float* __restrict__ Y, int M) {
    constexpr int TC = NC / 8;
    constexpr int THREADS = 32 * TC;
    constexpr int KC = 32;
    __shared__ float Xs[128][33];
    __shared__ float Ws[KC][NC];

    const int tid  = threadIdx.x;
    const int tr   = tid / TC;
    const int tc   = tid % TC;
    const int row0 = blockIdx.x * 128;

    float acc[4][8];
    #pragma unroll
    for (int i = 0; i < 4; ++i)
        #pragma unroll
        for (int j = 0; j < 8; ++j) acc[i][j] = 0.f;

    for (int kc = 0; kc < KD; kc += KC) {
        #pragma unroll
        for (int i = tid; i < 128 * (KC / 4); i += THREADS) {
            int r  = i / (KC / 4);
            int k4 = (i % (KC / 4)) * 4;
            float4 v = make_float4(0.f, 0.f, 0.f, 0.f);
            int gr = row0 + r;
            if (gr < M)
                v = *reinterpret_cast<const float4*>(&X[(size_t)gr * KD + kc + k4]);
            Xs[r][k4 + 0] = v.x; Xs[r][k4 + 1] = v.y;
            Xs[r][k4 + 2] = v.z; Xs[r][k4 + 3] = v.w;
        }
        #pragma unroll
        for (int i = tid; i < KC * (NC / 4); i += THREADS) {
            int kk = i / (NC / 4);
            int c4 = (i % (NC / 4)) * 4;
            *reinterpret_cast<float4*>(&Ws[kk][c4]) =
                *reinterpret_cast<const float4*>(&W[(size_t)(kc + kk) * NC + c4]);
        }
        __syncthreads();

        #pragma unroll
        for (int kk = 0; kk < KC; ++kk) {
            float xv[4];
            #pragma unroll
            for (int i = 0; i < 4; ++i) xv[i] = Xs[tr * 4 + i][kk];
            float4 w0 = *reinterpret_cast<const float4*>(&Ws[kk][tc * 8]);
            float4 w1 = *reinterpret_cast<const float4*>(&Ws[kk][tc * 8 + 4]);
            float wv[8] = {w0.x, w0.y, w0.z, w0.w, w1.x, w1.y, w1.z, w1.w};
            #pragma unroll
            for (int i = 0; i < 4; ++i)
                #pragma unroll
                for (int j = 0; j < 8; ++j)
                    acc[i][j] = fmaf(xv[i], wv[j], acc[i][j]);
        }
        __syncthreads();
    }

    #pragma unroll
    for (int i = 0; i < 4; ++i) {
        int gr = row0 + tr * 4 + i;
        if (gr < M) {
            float4 o0 = make_float4(acc[i][0], acc[i][1], acc[i][2], acc[i][3]);
            float4 o1 = make_float4(acc[i][4], acc[i][5], acc[i][6], acc[i][7]);
            *reinterpret_cast<float4*>(&Y[(size_t)gr * NC + tc * 8])     = o0;
            *reinterpret_cast<float4*>(&Y[(size_t)gr * NC + tc * 8 + 4]) = o1;
        }
    }
}

// ---------------- agg1 (+bias+relu) fused with GEMM2 -> H2 ----------------
// one wave per node; lane = feature. Summation order IDENTICAL to round-2
// (single acc, edges in CSR order); loads batched 8-deep for MLP.
// Tail slots: lanes >= m hold dsv=0, so fma(0,v,acc)==acc exactly.
__global__ __launch_bounds__(256)
void k_agg1(const float* __restrict__ H1, const int* __restrict__ rowptr,
            const int* __restrict__ csr, const float* __restrict__ dn,
            const float* __restrict__ b1, const float* __restrict__ W2,
            float* __restrict__ H2) {
    __shared__ float W2s[HID_DIM * OUT_DIM];   // 8 KB
    for (int i = threadIdx.x; i < HID_DIM * OUT_DIM; i += 256) W2s[i] = W2[i];
    __syncthreads();

    int wid  = (blockIdx.x * blockDim.x + threadIdx.x) >> 6;
    int lane = threadIdx.x & 63;
    if (wid >= N_NODES) return;
    const int n = wid;

    int rp = (lane < 2) ? rowptr[n + lane] : 0;
    int base = __shfl(rp, 0);
    int cnt  = __shfl(rp, 1) - base;
    const float dnn = dn[n];

    float acc = dnn * H1[(size_t)n * HID_DIM + lane];   // self-loop first (round-2 order)
    for (int b0 = 0; b0 < cnt; b0 += 64) {
        int m = min(64, cnt - b0);
        int s = 0; float dsv = 0.f;
        if (lane < m) { s = csr[base + b0 + lane]; dsv = dn[s]; }
        // j0 in {0,8,...,56}; j = j0+i <= 63 always (valid shfl source)
        for (int j0 = 0; j0 < m; j0 += 8) {
            float v[8], w[8];
            #pragma unroll
            for (int i = 0; i < 8; ++i) {
                int j  = j0 + i;
                int sj = __shfl(s, j);
                w[i] = __shfl(dsv, j);                 // 0 when j >= m
                v[i] = H1[(size_t)sj * HID_DIM + lane];
            }
            #pragma unroll
            for (int i = 0; i < 8; ++i) acc = fmaf(w[i], v[i], acc);
        }
    }
    float o = fmaxf(b1[lane] + dnn * acc, 0.f);   // out1 row, one per lane

    // fused GEMM2 (verbatim round-2): H2[n][c] = sum_f o_f W2[f][c]
    const int c = lane & 31, h = lane >> 5;
    float acc2 = 0.f;
    #pragma unroll
    for (int fi = 0; fi < 32; ++fi) {
        int fg = h * 32 + fi;
        float vv = __shfl(o, fg);
        acc2 = fmaf(vv, W2s[fg * OUT_DIM + c], acc2);
    }
    acc2 += __shfl_xor(acc2, 32);
    if (h == 0) H2[(size_t)n * OUT_DIM + c] = acc2;
}

// ---------------- agg2 (+bias) fused with MLP head ----------------
// one wave per node; lane&31 = feature, halves split edges by parity
// (round-2 semantics); loads batched 8-deep per parity stream.
// j0 in {h, h+16, h+32, h+48}; j = j0+2i <= 63 always (valid shfl source).
__global__ __launch_bounds__(256)
void k_agg2m(const float* __restrict__ H2, const int* __restrict__ rowptr,
             const int* __restrict__ csr, const float* __restrict__ dn,
             const float* __restrict__ b2, const float* __restrict__ Wp1,
             const float* __restrict__ bp1, const float* __restrict__ Wp2,
             const float* __restrict__ bp2, float* __restrict__ out_h,
             float* __restrict__ out_w) {
    __shared__ float Wp1s[OUT_DIM * HID_DIM];  // 8 KB
    __shared__ float Wp2s[HID_DIM];
    __shared__ float bp1s[HID_DIM];
    for (int i = threadIdx.x; i < OUT_DIM * HID_DIM; i += 256) Wp1s[i] = Wp1[i];
    if (threadIdx.x < HID_DIM) {
        Wp2s[threadIdx.x] = Wp2[threadIdx.x];
        bp1s[threadIdx.x] = bp1[threadIdx.x];
    }
    __syncthreads();

    int wid  = (blockIdx.x * blockDim.x + threadIdx.x) >> 6;
    int lane = threadIdx.x & 63;
    if (wid >= N_NODES) return;
    const int n = wid;

    int rp = (lane < 2) ? rowptr[n + lane] : 0;
    int base = __shfl(rp, 0);
    int cnt  = __shfl(rp, 1) - base;
    const float dnn = dn[n];
    const int f = lane & 31, h = lane >> 5;

    float acc = (h == 0) ? dnn * H2[(size_t)n * OUT_DIM + f] : 0.f;
    for (int b0 = 0; b0 < cnt; b0 += 64) {
        int m = min(64, cnt - b0);
        int s = 0; float dsv = 0.f;
        if (lane < m) { s = csr[base + b0 + lane]; dsv = dn[s]; }
        for (int j0 = h; j0 < m; j0 += 16) {
            float v[8], w[8];
            #pragma unroll
            for (int i = 0; i < 8; ++i) {
                int j  = j0 + 2 * i;
                int sj = __shfl(s, j);
                w[i] = __shfl(dsv, j);                 // 0 when j >= m
                v[i] = H2[(size_t)sj * OUT_DIM + f];
            }
            #pragma unroll
            for (int i = 0; i < 8; ++i) acc = fmaf(w[i], v[i], acc);
        }
    }
    acc += __shfl_xor(acc, 32);                 // both halves now hold full sum
    float hv = b2[f] + dnn * acc;               // h[n][f] on lane f and f+32
    if (h == 0) out_h[(size_t)n * OUT_DIM + f] = hv;

    // MLP (verbatim round-2): p[j] = relu(bp1[j] + sum_f h_f Wp1[f][j])
    float p = bp1s[lane];
    #pragma unroll
    for (int ff = 0; ff < OUT_DIM; ++ff) {
        float hf = __shfl(hv, ff);
        p = fmaf(hf, Wp1s[ff * HID_DIM + lane], p);
    }
    p = fmaxf(p, 0.f);
    float z = p * Wp2s[lane];
    #pragma unroll
    for (int off = 32; off; off >>= 1) z += __shfl_xor(z, off);
    if (lane == 0) out_w[n] = 1.f / (1.f + __expf(-(z + bp2[0])));
}

// ---------------- launcher ----------------
extern "C" void kernel_launch(void* const* d_in, const int* in_sizes, int n_in,
                              void* d_out, int out_size, void* d_ws, size_t ws_size,
                              hipStream_t stream) {
    const float* x   = (const float*)d_in[0];
    const int*   ei  = (const int*)d_in[1];
    const float* W1  = (const float*)d_in[2];
    const float* b1  = (const float*)d_in[3];
    const float* W2  = (const float*)d_in[4];
    const float* b2  = (const float*)d_in[5];
    const float* Wp1 = (const float*)d_in[6];
    const float* bp1 = (const float*)d_in[7];
    const float* Wp2 = (const float*)d_in[8];
    const float* bp2 = (const float*)d_in[9];
    float* out = (float*)d_out;

    char* ws = (char*)d_ws;
    int*   bin_cursor = (int*)  (ws + 0);           //  1,564 B
    int*   bin_base   = (int*)  (ws + 2048);        //  1,564 B
    int*   rowptr     = (int*)  (ws + 4096);        //  400,004 B
    float* dn         = (float*)(ws + 404480);      //  400,000 B
    int*   csr        = (int*)  (ws + 804608);      //  12,800,000 B
    int2*  binned     = (int2*) (ws + 13604608);    //  28,827,648 B
    float* H1         = (float*)(ws + 42432512);    //  25,600,000 B
    float* H2         = (float*)(ws + 68032512);    //  12,800,000 B
    // end ~80.8 MB

    hipMemsetAsync(bin_cursor, 0, NBINS * sizeof(int), stream);

    k_bin<<<(N_EDGES + BIN_EPB - 1) / BIN_EPB, 512, 0, stream>>>(ei, bin_cursor, binned);
    k_binscan<<<1, 512, 0, stream>>>(bin_cursor, bin_base, rowptr);
    k_csr<<<NBINS, 256, 0, stream>>>(binned, bin_cursor, bin_base, rowptr, dn, csr);

    k_gemm<IN_DIM, HID_DIM><<<(N_NODES + 127) / 128, 256, 0, stream>>>(x, W1, H1, N_NODES);

    k_agg1<<<(N_NODES + 3) / 4, 256, 0, stream>>>(H1, rowptr, csr, dn, b1, W2, H2);
    k_agg2m<<<(N_NODES + 3) / 4, 256, 0, stream>>>(H2, rowptr, csr, dn, b2,
                                                   Wp1, bp1, Wp2, bp2,
                                                   out, out + (size_t)N_NODES * OUT_DIM);
}